// Round 8
// baseline (79.277 us; speedup 1.0000x reference)
//
#include <hip/hip_runtime.h>
#include <math.h>

// Problem constants: D=2048, K=4096, C=1000, W=4096
constexpr int KN = 4096;
constexpr int DN = 2048;
constexpr int CN = 1000;
constexpr int WN = 4096;

// Exactly co-resident persistent grid: 256 CU x 4 blocks/CU.
// 256 thr (4 waves) x <=128 VGPR (launch_bounds 256,4) x 32KB LDS -> 4 blk/CU.
constexpr int NBLK = 1024;
constexpr int NTHR = 256;

__device__ __forceinline__ float waveSum(float v) {
#pragma unroll
    for (int o = 32; o > 0; o >>= 1) v += __shfl_xor(v, o, 64);
    return v;
}
__device__ __forceinline__ float waveMax(float v) {
#pragma unroll
    for (int o = 32; o > 0; o >>= 1) v = fmaxf(v, __shfl_xor(v, o, 64));
    return v;
}

// Fused: stage A (d + ce) -> global software barrier -> stage B (w rows)
// -> last-block final reduce. Cross-block data moves ONLY via agent-scope
// atomics (coherent point) — no cache-flush fences anywhere.
__global__ __launch_bounds__(NTHR, 4) void fused_kernel(
    const float* __restrict__ deep, const float* __restrict__ nmat,
    const float* __restrict__ cls, const int* __restrict__ target,
    const float* __restrict__ wmat,
    float* __restrict__ d_arr, float* __restrict__ ce_arr,
    float* __restrict__ part, unsigned int* __restrict__ cnt,
    float* __restrict__ out)
{
    __shared__ float sd[KN];       // 16 KB
    __shared__ float sc[KN];       // 16 KB
    __shared__ float wpart[4];
    __shared__ int   sLast;

    const int b    = blockIdx.x;
    const int tid  = threadIdx.x;
    const int wv   = tid >> 6;
    const int lane = tid & 63;
    const int row  = b * 4 + wv;   // this wave's row for ALL phases (0..4095)

    // ---------------- stage A1: distance row ----------------
    {
        const float4* nrow = (const float4*)(nmat + (size_t)row * DN);
        const float4* df   = (const float4*)deep;
        float acc = 0.f;
#pragma unroll
        for (int c = 0; c < 8; ++c) {
            const int i = lane + 64 * c;
            const float4 a = df[i];
            const float4 x = nrow[i];
            const float e0 = a.x - x.x, e1 = a.y - x.y, e2 = a.z - x.z, e3 = a.w - x.w;
            acc += e0 * e0 + e1 * e1 + e2 * e2 + e3 * e3;
        }
        acc = waveSum(acc);
        if (lane == 0)
            __hip_atomic_store(&d_arr[row], sqrtf(acc),
                               __ATOMIC_RELAXED, __HIP_MEMORY_SCOPE_AGENT);
    }

    // ---------------- stage A2: CE row ----------------
    {
        const float4* x4 = (const float4*)(cls + (size_t)row * CN);
        float4 v[4];
#pragma unroll
        for (int j = 0; j < 4; ++j) {
            const int i = lane + 64 * j;
            v[j] = (i < CN / 4) ? x4[i]
                                : make_float4(-INFINITY, -INFINITY, -INFINITY, -INFINITY);
        }
        float mx = -INFINITY;
#pragma unroll
        for (int j = 0; j < 4; ++j)
            mx = fmaxf(mx, fmaxf(fmaxf(v[j].x, v[j].y), fmaxf(v[j].z, v[j].w)));
        const float m = waveMax(mx);
        float s = 0.f;
#pragma unroll
        for (int j = 0; j < 4; ++j)
            s += __expf(v[j].x - m) + __expf(v[j].y - m)
               + __expf(v[j].z - m) + __expf(v[j].w - m);
        s = waveSum(s);
        if (lane == 0)
            ce_arr[row] = 0.f,   // dead store eliminated pattern avoided; real store below
            __hip_atomic_store(&ce_arr[row], m + __logf(s) - cls[(size_t)row * CN + target[0]],
                               __ATOMIC_RELAXED, __HIP_MEMORY_SCOPE_AGENT);
    }

    // per-wave drain (insurance; __syncthreads also drains vmcnt)
    asm volatile("s_waitcnt vmcnt(0)");
    __syncthreads();

    // ---------------- global barrier (fence-free) ----------------
    if (tid == 0) {
        __hip_atomic_fetch_add(cnt, 1u, __ATOMIC_RELAXED, __HIP_MEMORY_SCOPE_AGENT);
        while (__hip_atomic_load(cnt, __ATOMIC_RELAXED, __HIP_MEMORY_SCOPE_AGENT)
               < (unsigned)NBLK)
            __builtin_amdgcn_s_sleep(8);
    }
    __syncthreads();

    // ---------------- stage d/ce into LDS (coherent loads) ----------------
#pragma unroll
    for (int j = 0; j < 16; ++j) {
        const int i = tid + NTHR * j;
        sd[i] = __hip_atomic_load(&d_arr[i],  __ATOMIC_RELAXED, __HIP_MEMORY_SCOPE_AGENT);
        sc[i] = __hip_atomic_load(&ce_arr[i], __ATOMIC_RELAXED, __HIP_MEMORY_SCOPE_AGENT);
    }
    __syncthreads();

    // ---------------- stage B: this wave's w row ----------------
    {
        const float4* wrow = (const float4*)(wmat + (size_t)row * KN);
        const float4* sd4  = (const float4*)sd;
        const float4* sc4  = (const float4*)sc;
        float es = 0.f, ec = 0.f, fs = 0.f;
#pragma unroll
        for (int c = 0; c < 16; ++c) {   // 1024 float4 / 64 lanes
            const int i = lane + 64 * c;
            const float4 a  = wrow[i];
            const float4 dv = sd4[i];
            const float4 cv = sc4[i];
            float t, e;
            t = a.x * dv.x; fs += t; e = __expf(-t); es += e; ec += e * cv.x;
            t = a.y * dv.y; fs += t; e = __expf(-t); es += e; ec += e * cv.y;
            t = a.z * dv.z; fs += t; e = __expf(-t); es += e; ec += e * cv.z;
            t = a.w * dv.w; fs += t; e = __expf(-t); es += e; ec += e * cv.w;
        }
        es = waveSum(es);  ec = waveSum(ec);  fs = waveSum(fs);
        if (lane == 0) wpart[wv] = ec / es + fs;
    }
    __syncthreads();

    // ---------------- block partial + last-block final reduce ----------------
    if (tid == 0) {
        const float psum = wpart[0] + wpart[1] + wpart[2] + wpart[3];
        __hip_atomic_store(&part[b], psum, __ATOMIC_RELAXED, __HIP_MEMORY_SCOPE_AGENT);
        asm volatile("s_waitcnt vmcnt(0)");
        const unsigned prev = __hip_atomic_fetch_add(cnt + 1, 1u, __ATOMIC_RELAXED,
                                                     __HIP_MEMORY_SCOPE_AGENT);
        sLast = (prev == (unsigned)(NBLK - 1)) ? 1 : 0;
    }
    __syncthreads();
    if (sLast) {
        float acc = 0.f;
#pragma unroll
        for (int j = 0; j < 4; ++j)
            acc += __hip_atomic_load(&part[tid + NTHR * j],
                                     __ATOMIC_RELAXED, __HIP_MEMORY_SCOPE_AGENT);
        acc = waveSum(acc);
        if (lane == 0) wpart[wv] = acc;
        __syncthreads();
        if (tid == 0) out[0] = wpart[0] + wpart[1] + wpart[2] + wpart[3];
    }
}

extern "C" void kernel_launch(void* const* d_in, const int* in_sizes, int n_in,
                              void* d_out, int out_size, void* d_ws, size_t ws_size,
                              hipStream_t stream) {
    const float* deep   = (const float*)d_in[0];   // [1, D]
    const float* cls    = (const float*)d_in[1];   // [K, C]
    const int*   target = (const int*)d_in[2];     // [1]
    const float* nmat   = (const float*)d_in[3];   // [K, D]
    const float* wmat   = (const float*)d_in[4];   // [W, K]

    float* ws     = (float*)d_ws;
    float* d_arr  = ws;                    // [K]
    float* ce_arr = ws + KN;               // [K]
    float* part   = ws + 2 * KN;           // [NBLK]
    unsigned int* cnt = (unsigned int*)(ws + 2 * KN + NBLK);   // [2]

    // zero both barrier counters each call (graph-capturable)
    hipMemsetAsync(cnt, 0, 2 * sizeof(unsigned int), stream);

    fused_kernel<<<NBLK, NTHR, 0, stream>>>(
        deep, nmat, cls, target, wmat, d_arr, ce_arr, part, cnt, (float*)d_out);
}

// Round 9
// 38.827 us; speedup vs baseline: 2.0418x; 2.0418x over previous
//
#include <hip/hip_runtime.h>
#include <math.h>

// Problem constants: D=2048, K=4096, C=1000, W=4096
constexpr int KN = 4096;
constexpr int DN = 2048;
constexpr int CN = 1000;
constexpr int WN = 4096;

// Persistent fused kernel: 256 blocks (= #CUs) x 1024 threads (16 waves).
// 32KB LDS + ~<=96 VGPR -> every block co-resident (1 per CU).
constexpr int NBLK = 256;
constexpr int NTHR = 1024;
constexpr int ROWS_PER_BLK = KN / NBLK;   // 16 = one row per wave

__device__ __forceinline__ float waveSum(float v) {
#pragma unroll
    for (int o = 32; o > 0; o >>= 1) v += __shfl_xor(v, o, 64);
    return v;
}
__device__ __forceinline__ float waveMax(float v) {
#pragma unroll
    for (int o = 32; o > 0; o >>= 1) v = fmaxf(v, __shfl_xor(v, o, 64));
    return v;
}

// Phase A: wave wv of block b computes d[row], ce[row] (row = b*16+wv),
// publishing via agent-scope atomic stores (write at coherent point/LLC).
// Barrier: per-block flag store + one-wave poll (no RMW burst).
// Post-barrier: NORMAL cached float4 loads stage d/ce into LDS — safe because
// dispatch-start acquire invalidated L1/L2 and these lines were never read
// pre-barrier, so the miss path fetches the fresh LLC values.
// Phase B: wave processes w-row (b*16+wv); block partial -> part[b];
// last block (relaxed RMW counter) reduces the 256 partials.
__global__ __launch_bounds__(NTHR) void fused_kernel(
    const float* __restrict__ deep, const float* __restrict__ nmat,
    const float* __restrict__ cls, const int* __restrict__ target,
    const float* __restrict__ wmat,
    float* __restrict__ d_arr, float* __restrict__ ce_arr,
    float* __restrict__ part, unsigned int* __restrict__ flags,
    unsigned int* __restrict__ cnt2, float* __restrict__ out)
{
    __shared__ float sd[KN];        // 16 KB
    __shared__ float sc[KN];        // 16 KB
    __shared__ float wpart[16];
    __shared__ int   sLast;

    const int b    = blockIdx.x;
    const int tid  = threadIdx.x;
    const int wv   = tid >> 6;
    const int lane = tid & 63;
    const int row  = b * ROWS_PER_BLK + wv;    // 0..4095

    // ---------------- phase A1: distance row ----------------
    {
        const float4* nrow = (const float4*)(nmat + (size_t)row * DN);
        const float4* df   = (const float4*)deep;
        float acc = 0.f;
#pragma unroll
        for (int c = 0; c < 8; ++c) {
            const int i = lane + 64 * c;
            const float4 a = df[i];
            const float4 x = nrow[i];
            const float e0 = a.x - x.x, e1 = a.y - x.y, e2 = a.z - x.z, e3 = a.w - x.w;
            acc += e0 * e0 + e1 * e1 + e2 * e2 + e3 * e3;
        }
        acc = waveSum(acc);
        if (lane == 0)
            __hip_atomic_store(&d_arr[row], sqrtf(acc),
                               __ATOMIC_RELAXED, __HIP_MEMORY_SCOPE_AGENT);
    }

    // ---------------- phase A2: CE row ----------------
    {
        const float4* x4 = (const float4*)(cls + (size_t)row * CN);
        float4 v[4];
#pragma unroll
        for (int j = 0; j < 4; ++j) {
            const int i = lane + 64 * j;
            v[j] = (i < CN / 4) ? x4[i]
                                : make_float4(-INFINITY, -INFINITY, -INFINITY, -INFINITY);
        }
        float mx = -INFINITY;
#pragma unroll
        for (int j = 0; j < 4; ++j)
            mx = fmaxf(mx, fmaxf(fmaxf(v[j].x, v[j].y), fmaxf(v[j].z, v[j].w)));
        const float m = waveMax(mx);
        float s = 0.f;
#pragma unroll
        for (int j = 0; j < 4; ++j)    // exp(-inf - m) == 0, pads vanish
            s += __expf(v[j].x - m) + __expf(v[j].y - m)
               + __expf(v[j].z - m) + __expf(v[j].w - m);
        s = waveSum(s);
        if (lane == 0)
            __hip_atomic_store(&ce_arr[row],
                               m + __logf(s) - cls[(size_t)row * CN + target[0]],
                               __ATOMIC_RELAXED, __HIP_MEMORY_SCOPE_AGENT);
    }

    // drain this wave's stores to the coherent point, then block-arrive
    asm volatile("s_waitcnt vmcnt(0)" ::: "memory");
    __syncthreads();
    if (tid == 0)
        __hip_atomic_store(&flags[b], 1u, __ATOMIC_RELAXED, __HIP_MEMORY_SCOPE_AGENT);

    // ---------------- global barrier: wave 0 polls all 256 flags ----------------
    if (wv == 0) {
        for (;;) {
            unsigned f = 1u;
#pragma unroll
            for (int j = 0; j < 4; ++j)
                f &= __hip_atomic_load(&flags[lane + 64 * j],
                                       __ATOMIC_RELAXED, __HIP_MEMORY_SCOPE_AGENT);
            if (__all(f != 0u)) break;
            __builtin_amdgcn_s_sleep(2);
        }
    }
    __syncthreads();   // releases waves 1..15; orders staging loads after poll

    // ---------------- stage d/ce into LDS (normal cached vector loads) --------
    {
        const float4* d4  = (const float4*)d_arr;
        const float4* c4  = (const float4*)ce_arr;
        float4* sd4 = (float4*)sd;
        float4* sc4 = (float4*)sc;
        sd4[tid] = d4[tid];            // 1024 float4
        sc4[tid] = c4[tid];            // 1024 float4
    }
    __syncthreads();

    // ---------------- phase B: this wave's w row ----------------
    {
        const float4* wrow = (const float4*)(wmat + (size_t)row * KN);
        const float4* sd4  = (const float4*)sd;
        const float4* sc4  = (const float4*)sc;
        float es = 0.f, ec = 0.f, fs = 0.f;
#pragma unroll
        for (int c = 0; c < 16; ++c) {    // 1024 float4 / 64 lanes
            const int i = lane + 64 * c;
            const float4 a  = wrow[i];
            const float4 dv = sd4[i];
            const float4 cv = sc4[i];
            float t, e;
            t = a.x * dv.x; fs += t; e = __expf(-t); es += e; ec += e * cv.x;
            t = a.y * dv.y; fs += t; e = __expf(-t); es += e; ec += e * cv.y;
            t = a.z * dv.z; fs += t; e = __expf(-t); es += e; ec += e * cv.z;
            t = a.w * dv.w; fs += t; e = __expf(-t); es += e; ec += e * cv.w;
        }
        es = waveSum(es);  ec = waveSum(ec);  fs = waveSum(fs);
        if (lane == 0) wpart[wv] = ec / es + fs;   // no-max softmax: s in (-70,0]
    }
    __syncthreads();

    // ---------------- block partial + last-block final reduce ----------------
    if (tid == 0) {
        float psum = 0.f;
#pragma unroll
        for (int j = 0; j < 16; ++j) psum += wpart[j];
        __hip_atomic_store(&part[b], psum, __ATOMIC_RELAXED, __HIP_MEMORY_SCOPE_AGENT);
        asm volatile("s_waitcnt vmcnt(0)" ::: "memory");
        const unsigned prev = __hip_atomic_fetch_add(cnt2, 1u, __ATOMIC_RELAXED,
                                                     __HIP_MEMORY_SCOPE_AGENT);
        sLast = (prev == (unsigned)(NBLK - 1)) ? 1 : 0;
    }
    __syncthreads();
    if (sLast && wv == 0) {
        float acc = 0.f;
#pragma unroll
        for (int j = 0; j < 4; ++j)
            acc += __hip_atomic_load(&part[lane + 64 * j],
                                     __ATOMIC_RELAXED, __HIP_MEMORY_SCOPE_AGENT);
        acc = waveSum(acc);
        if (lane == 0) out[0] = acc;
    }
}

extern "C" void kernel_launch(void* const* d_in, const int* in_sizes, int n_in,
                              void* d_out, int out_size, void* d_ws, size_t ws_size,
                              hipStream_t stream) {
    const float* deep   = (const float*)d_in[0];   // [1, D]
    const float* cls    = (const float*)d_in[1];   // [K, C]
    const int*   target = (const int*)d_in[2];     // [1]
    const float* nmat   = (const float*)d_in[3];   // [K, D]
    const float* wmat   = (const float*)d_in[4];   // [W, K]

    float* ws     = (float*)d_ws;
    float* d_arr  = ws;                        // [4096]
    float* ce_arr = ws + KN;                   // [4096]
    float* part   = ws + 2 * KN;               // [256]
    unsigned int* flags = (unsigned int*)(ws + 2 * KN + NBLK);   // [256]
    unsigned int* cnt2  = flags + NBLK;                          // [1]

    // zero flags + last-block counter every call (graph-capturable)
    hipMemsetAsync(flags, 0, (NBLK + 1) * sizeof(unsigned int), stream);

    fused_kernel<<<NBLK, NTHR, 0, stream>>>(
        deep, nmat, cls, target, wmat, d_arr, ce_arr, part, flags, cnt2,
        (float*)d_out);
}

// Round 10
// 30.782 us; speedup vs baseline: 2.5754x; 1.2613x over previous
//
#include <hip/hip_runtime.h>
#include <math.h>

// Problem constants: D=2048, K=4096, C=1000, W=4096
constexpr int KN = 4096;
constexpr int DN = 2048;
constexpr int CN = 1000;
constexpr int WN = 4096;

// Persistent fused kernel: 256 blocks (<= 1/CU) x 1024 threads (16 waves).
constexpr int NBLK = 256;
constexpr int NTHR = 1024;
constexpr int ROWS_PER_BLK = KN / NBLK;   // 16 = one row per wave

constexpr unsigned MAGIC = 0x5A5A0001u;

// ctrl layout (uint words, 64B line spacing):
//   ctrl[0]   = arrival counter (barrier)
//   ctrl[16]  = last-block counter (final reduce)
//   ctrl[32 + 16*x] = release flag for poll-group x (x = 0..7)
#define CTRL_CNT   0
#define CTRL_CNT2  16
#define CTRL_REL(x) (32 + 16 * (x))

__device__ __forceinline__ float waveSum(float v) {
#pragma unroll
    for (int o = 32; o > 0; o >>= 1) v += __shfl_xor(v, o, 64);
    return v;
}
__device__ __forceinline__ float waveMax(float v) {
#pragma unroll
    for (int o = 32; o > 0; o >>= 1) v = fmaxf(v, __shfl_xor(v, o, 64));
    return v;
}

__global__ __launch_bounds__(NTHR) void fused_kernel(
    const float* __restrict__ deep, const float* __restrict__ nmat,
    const float* __restrict__ cls, const int* __restrict__ target,
    const float* __restrict__ wmat,
    float* __restrict__ d_arr, float* __restrict__ ce_arr,
    float* __restrict__ part, unsigned int* __restrict__ ctrl,
    float* __restrict__ out)
{
    __shared__ float sd[KN];        // 16 KB
    __shared__ float sc[KN];        // 16 KB
    __shared__ float wpart[16];
    __shared__ int   sLast;

    const int b    = blockIdx.x;
    const int tid  = threadIdx.x;
    const int wv   = tid >> 6;
    const int lane = tid & 63;
    const int row  = b * ROWS_PER_BLK + wv;    // 0..4095

    // ---- counter/flag reset by block 0 at entry. Safe: all blocks start
    // within <1us of dispatch; first arrival is >=3us away (phase A reads
    // 192KB/block). Stale/poisoned flags can never be polled before this.
    if (b == 0 && tid < 10) {
        const int idx = (tid < 2) ? (tid ? CTRL_CNT2 : CTRL_CNT) : CTRL_REL(tid - 2);
        __hip_atomic_store(&ctrl[idx], 0u, __ATOMIC_RELAXED, __HIP_MEMORY_SCOPE_AGENT);
    }

    // ---------------- phase A1: distance row ----------------
    {
        const float4* nrow = (const float4*)(nmat + (size_t)row * DN);
        const float4* df   = (const float4*)deep;
        float acc = 0.f;
#pragma unroll
        for (int c = 0; c < 8; ++c) {
            const int i = lane + 64 * c;
            const float4 a = df[i];
            const float4 x = nrow[i];
            const float e0 = a.x - x.x, e1 = a.y - x.y, e2 = a.z - x.z, e3 = a.w - x.w;
            acc += e0 * e0 + e1 * e1 + e2 * e2 + e3 * e3;
        }
        acc = waveSum(acc);
        if (lane == 0)
            __hip_atomic_store(&d_arr[row], sqrtf(acc),
                               __ATOMIC_RELAXED, __HIP_MEMORY_SCOPE_AGENT);
    }

    // ---------------- phase A2: CE row ----------------
    {
        const float4* x4 = (const float4*)(cls + (size_t)row * CN);
        float4 v[4];
#pragma unroll
        for (int j = 0; j < 4; ++j) {
            const int i = lane + 64 * j;
            v[j] = (i < CN / 4) ? x4[i]
                                : make_float4(-INFINITY, -INFINITY, -INFINITY, -INFINITY);
        }
        float mx = -INFINITY;
#pragma unroll
        for (int j = 0; j < 4; ++j)
            mx = fmaxf(mx, fmaxf(fmaxf(v[j].x, v[j].y), fmaxf(v[j].z, v[j].w)));
        const float m = waveMax(mx);
        float s = 0.f;
#pragma unroll
        for (int j = 0; j < 4; ++j)    // exp(-inf - m) == 0, pads vanish
            s += __expf(v[j].x - m) + __expf(v[j].y - m)
               + __expf(v[j].z - m) + __expf(v[j].w - m);
        s = waveSum(s);
        if (lane == 0)
            __hip_atomic_store(&ce_arr[row],
                               m + __logf(s) - cls[(size_t)row * CN + target[0]],
                               __ATOMIC_RELAXED, __HIP_MEMORY_SCOPE_AGENT);
    }

    // per-wave drain of the publish stores, then block-level rendezvous
    asm volatile("s_waitcnt vmcnt(0)" ::: "memory");
    __syncthreads();

    // ---------------- global barrier: 1 RMW arrival + 1-line poll ----------
    if (tid == 0) {
        const unsigned prev = __hip_atomic_fetch_add(&ctrl[CTRL_CNT], 1u,
                                                     __ATOMIC_RELAXED,
                                                     __HIP_MEMORY_SCOPE_AGENT);
        if (prev == (unsigned)(NBLK - 1)) {
#pragma unroll
            for (int x = 0; x < 8; ++x)
                __hip_atomic_store(&ctrl[CTRL_REL(x)], MAGIC,
                                   __ATOMIC_RELAXED, __HIP_MEMORY_SCOPE_AGENT);
        } else {
            volatile unsigned* relp = (volatile unsigned*)&ctrl[CTRL_REL(b & 7)];
            while (__hip_atomic_load((unsigned*)relp, __ATOMIC_RELAXED,
                                     __HIP_MEMORY_SCOPE_AGENT) != MAGIC)
                __builtin_amdgcn_s_sleep(16);
        }
    }
    __syncthreads();   // releases the other 15 waves

    // ---------------- stage d/ce into LDS (normal cached vector loads) ------
    {
        const float4* d4  = (const float4*)d_arr;
        const float4* c4  = (const float4*)ce_arr;
        ((float4*)sd)[tid] = d4[tid];          // 1024 float4
        ((float4*)sc)[tid] = c4[tid];          // 1024 float4
    }
    __syncthreads();

    // ---------------- phase B: this wave's w row ----------------
    {
        const float4* wrow = (const float4*)(wmat + (size_t)row * KN);
        const float4* sd4  = (const float4*)sd;
        const float4* sc4  = (const float4*)sc;
        float es = 0.f, ec = 0.f, fs = 0.f;
#pragma unroll
        for (int c = 0; c < 16; ++c) {    // 1024 float4 / 64 lanes
            const int i = lane + 64 * c;
            const float4 a  = wrow[i];
            const float4 dv = sd4[i];
            const float4 cv = sc4[i];
            float t, e;
            t = a.x * dv.x; fs += t; e = __expf(-t); es += e; ec += e * cv.x;
            t = a.y * dv.y; fs += t; e = __expf(-t); es += e; ec += e * cv.y;
            t = a.z * dv.z; fs += t; e = __expf(-t); es += e; ec += e * cv.z;
            t = a.w * dv.w; fs += t; e = __expf(-t); es += e; ec += e * cv.w;
        }
        es = waveSum(es);  ec = waveSum(ec);  fs = waveSum(fs);
        if (lane == 0) wpart[wv] = ec / es + fs;   // no-max softmax: s in (-70,0]
    }
    __syncthreads();

    // ---------------- block partial + last-block final reduce ---------------
    if (tid == 0) {
        float psum = 0.f;
#pragma unroll
        for (int j = 0; j < 16; ++j) psum += wpart[j];
        __hip_atomic_store(&part[b], psum, __ATOMIC_RELAXED, __HIP_MEMORY_SCOPE_AGENT);
        asm volatile("s_waitcnt vmcnt(0)" ::: "memory");
        const unsigned prev = __hip_atomic_fetch_add(&ctrl[CTRL_CNT2], 1u,
                                                     __ATOMIC_RELAXED,
                                                     __HIP_MEMORY_SCOPE_AGENT);
        sLast = (prev == (unsigned)(NBLK - 1)) ? 1 : 0;
    }
    __syncthreads();
    if (sLast && wv == 0) {
        float acc = 0.f;
#pragma unroll
        for (int j = 0; j < 4; ++j)
            acc += __hip_atomic_load(&part[lane + 64 * j],
                                     __ATOMIC_RELAXED, __HIP_MEMORY_SCOPE_AGENT);
        acc = waveSum(acc);
        if (lane == 0) out[0] = acc;
    }
}

extern "C" void kernel_launch(void* const* d_in, const int* in_sizes, int n_in,
                              void* d_out, int out_size, void* d_ws, size_t ws_size,
                              hipStream_t stream) {
    const float* deep   = (const float*)d_in[0];   // [1, D]
    const float* cls    = (const float*)d_in[1];   // [K, C]
    const int*   target = (const int*)d_in[2];     // [1]
    const float* nmat   = (const float*)d_in[3];   // [K, D]
    const float* wmat   = (const float*)d_in[4];   // [W, K]

    float* ws     = (float*)d_ws;
    float* d_arr  = ws;                        // [4096]
    float* ce_arr = ws + KN;                   // [4096]
    float* part   = ws + 2 * KN;               // [256]
    unsigned int* ctrl = (unsigned int*)(ws + 2 * KN + NBLK);   // [160] uints

    fused_kernel<<<NBLK, NTHR, 0, stream>>>(
        deep, nmat, cls, target, wmat, d_arr, ce_arr, part, ctrl, (float*)d_out);
}